// Round 5
// baseline (7435.312 us; speedup 1.0000x reference)
//
#include <hip/hip_runtime.h>

// B=64, T=64 -> GEMM M=4096, N=2048, K=2048 ; tdBN ; LIF scan. Full f64
// (r1/r4: absmax == 0.0). Round 5 = within-probe A/B of two GEMM variants,
// both launched (A first, B second overwrites H and is authoritative):
//   gemm_a: 8x4 microtile, 128x64 tile, BK=8  -> 64-reg acc, 4 waves/SIMD
//           (tests: occupancy-bound theory)
//   gemm_b: 8x8 microtile, 128x128 tile, BK=8 -> permuted LDS + ds_read_b128
//           (tests: issue-path theory at 2 waves/SIMD)
// Both: k-major LDS, bijective padded row-permutation so fragment reads are
// contiguous 16B-aligned b128 with <=2-way banks (free per m136).

#define KDIM 2048
#define NDIM 2048

// rows 0..127: group g=r%16 (owner thread), slot h=r/16 (0..7); pad 2/4 groups
__device__ __forceinline__ int permA(int r) {
    const int g = r & 15, h = r >> 4;
    return g * 8 + h + ((g >> 2) << 1);          // max 133 -> dim 136
}
// rows 0..63: g=r%16, h=r/16 (0..3)
__device__ __forceinline__ int permB64(int r) {
    const int g = r & 15, h = r >> 4;
    return g * 4 + h + ((g >> 2) << 1);          // max 69 -> dim 72
}

// ---------------- Variant A: 8x4 microtile, 128x64 tile ----------------
__global__ __launch_bounds__(256, 4) void gemm_a(
    const float* __restrict__ X, const float* __restrict__ W,
    const float* __restrict__ bias, double* __restrict__ H)
{
    __shared__ __align__(16) double As[2][8][136];
    __shared__ __align__(16) double Bs[2][8][72];

    const int tid = threadIdx.x;
    const int tx = tid & 15, ty = tid >> 4;
    const int bm = blockIdx.x * 128, bn = blockIdx.y * 64;

    const int arow = tid >> 1, akof = (tid & 1) * 4;   // A: float4 per tile
    const int brow = tid >> 2, bkof = (tid & 3) * 2;   // B: float2 per tile
    const float* xa = X + (size_t)(bm + arow) * KDIM + akof;
    const float* wa = W + (size_t)(bn + brow) * KDIM + bkof;
    const int apw = permA(arow);
    const int bpw = permB64(brow);
    const int aro = ty * 8 + ((ty >> 2) << 1);   // read base (8 doubles)
    const int bro = tx * 4 + ((tx >> 2) << 1);   // read base (4 doubles)

    double acc[8][4] = {};

    {   // prologue: stage tile 0
        float4 av = *(const float4*)xa;
        float2 bv = *(const float2*)wa;
        As[0][akof + 0][apw] = (double)av.x; As[0][akof + 1][apw] = (double)av.y;
        As[0][akof + 2][apw] = (double)av.z; As[0][akof + 3][apw] = (double)av.w;
        Bs[0][bkof + 0][bpw] = (double)bv.x; Bs[0][bkof + 1][bpw] = (double)bv.y;
    }
    __syncthreads();

    int cur = 0;
    for (int t = 0; t < 256; ++t) {
        const bool more = (t + 1) < 256;
        float4 av; float2 bv;
        if (more) {
            av = *(const float4*)(xa + (t + 1) * 8);
            bv = *(const float2*)(wa + (t + 1) * 8);
        }
        #pragma unroll
        for (int kk = 0; kk < 8; ++kk) {
            double a[8], b[4];
            const double2* pa = (const double2*)&As[cur][kk][aro];
            const double2* pb = (const double2*)&Bs[cur][kk][bro];
            *(double2*)&a[0] = pa[0]; *(double2*)&a[2] = pa[1];
            *(double2*)&a[4] = pa[2]; *(double2*)&a[6] = pa[3];
            *(double2*)&b[0] = pb[0]; *(double2*)&b[2] = pb[1];
            #pragma unroll
            for (int i = 0; i < 8; ++i)
                #pragma unroll
                for (int j = 0; j < 4; ++j)
                    acc[i][j] = fma(a[i], b[j], acc[i][j]);
        }
        if (more) {
            As[cur ^ 1][akof + 0][apw] = (double)av.x;
            As[cur ^ 1][akof + 1][apw] = (double)av.y;
            As[cur ^ 1][akof + 2][apw] = (double)av.z;
            As[cur ^ 1][akof + 3][apw] = (double)av.w;
            Bs[cur ^ 1][bkof + 0][bpw] = (double)bv.x;
            Bs[cur ^ 1][bkof + 1][bpw] = (double)bv.y;
        }
        __syncthreads();
        cur ^= 1;
    }

    #pragma unroll
    for (int j = 0; j < 4; ++j) {
        const int col = bn + tx + 16 * j;
        const double bj = (double)bias[col];
        #pragma unroll
        for (int i = 0; i < 8; ++i)
            H[(size_t)(bm + ty + 16 * i) * NDIM + col] = acc[i][j] + bj;
    }
}

// ---------------- Variant B: 8x8 microtile, 128x128 tile ----------------
__global__ __launch_bounds__(256, 2) void gemm_b(
    const float* __restrict__ X, const float* __restrict__ W,
    const float* __restrict__ bias, double* __restrict__ H)
{
    __shared__ __align__(16) double As[2][8][136];
    __shared__ __align__(16) double Bs[2][8][136];

    const int tid = threadIdx.x;
    const int tx = tid & 15, ty = tid >> 4;
    const int bm = blockIdx.x * 128, bn = blockIdx.y * 128;

    const int arow = tid >> 1, akof = (tid & 1) * 4;   // one float4 per matrix
    const float* xa = X + (size_t)(bm + arow) * KDIM + akof;
    const float* wa = W + (size_t)(bn + arow) * KDIM + akof;
    const int apw = permA(arow);
    const int aro = ty * 8 + ((ty >> 2) << 1);
    const int bro = tx * 8 + ((tx >> 2) << 1);

    double acc[8][8] = {};

    {   // prologue
        float4 av = *(const float4*)xa;
        float4 bv = *(const float4*)wa;
        As[0][akof + 0][apw] = (double)av.x; As[0][akof + 1][apw] = (double)av.y;
        As[0][akof + 2][apw] = (double)av.z; As[0][akof + 3][apw] = (double)av.w;
        Bs[0][akof + 0][apw] = (double)bv.x; Bs[0][akof + 1][apw] = (double)bv.y;
        Bs[0][akof + 2][apw] = (double)bv.z; Bs[0][akof + 3][apw] = (double)bv.w;
    }
    __syncthreads();

    int cur = 0;
    for (int t = 0; t < 256; ++t) {
        const bool more = (t + 1) < 256;
        float4 av, bv;
        if (more) {
            av = *(const float4*)(xa + (t + 1) * 8);
            bv = *(const float4*)(wa + (t + 1) * 8);
        }
        #pragma unroll
        for (int kk = 0; kk < 8; ++kk) {
            double a[8], b[8];
            const double2* pa = (const double2*)&As[cur][kk][aro];
            const double2* pb = (const double2*)&Bs[cur][kk][bro];
            *(double2*)&a[0] = pa[0]; *(double2*)&a[2] = pa[1];
            *(double2*)&a[4] = pa[2]; *(double2*)&a[6] = pa[3];
            *(double2*)&b[0] = pb[0]; *(double2*)&b[2] = pb[1];
            *(double2*)&b[4] = pb[2]; *(double2*)&b[6] = pb[3];
            #pragma unroll
            for (int i = 0; i < 8; ++i)
                #pragma unroll
                for (int j = 0; j < 8; ++j)
                    acc[i][j] = fma(a[i], b[j], acc[i][j]);
        }
        if (more) {
            As[cur ^ 1][akof + 0][apw] = (double)av.x;
            As[cur ^ 1][akof + 1][apw] = (double)av.y;
            As[cur ^ 1][akof + 2][apw] = (double)av.z;
            As[cur ^ 1][akof + 3][apw] = (double)av.w;
            Bs[cur ^ 1][akof + 0][apw] = (double)bv.x;
            Bs[cur ^ 1][akof + 1][apw] = (double)bv.y;
            Bs[cur ^ 1][akof + 2][apw] = (double)bv.z;
            Bs[cur ^ 1][akof + 3][apw] = (double)bv.w;
        }
        __syncthreads();
        cur ^= 1;
    }

    #pragma unroll
    for (int j = 0; j < 8; ++j) {
        const int col = bn + tx + 16 * j;
        const double bj = (double)bias[col];
        #pragma unroll
        for (int i = 0; i < 8; ++i)
            H[(size_t)(bm + ty + 16 * i) * NDIM + col] = acc[i][j] + bj;
    }
}

// ---------------- epilogue chain (unchanged, verified) ----------------
__global__ __launch_bounds__(256) void bn_partial(
    const double* __restrict__ H, double* __restrict__ psum, double* __restrict__ psq)
{
    constexpr int N = 2048, ROWS = 128;
    const int o  = blockIdx.x * 256 + threadIdx.x;
    const int t0 = blockIdx.y * ROWS;
    double s = 0.0, q = 0.0;
    for (int r = 0; r < ROWS; ++r) {
        double h = H[(size_t)(t0 + r) * N + o];
        s += h;
        q = fma(h, h, q);
    }
    psum[(size_t)blockIdx.y * N + o] = s;
    psq [(size_t)blockIdx.y * N + o] = q;
}

__global__ void bn_finalize(const double* __restrict__ psum, const double* __restrict__ psq,
                            double* __restrict__ meanv, double* __restrict__ varv)
{
    constexpr int N = 2048, CH = 32;
    const int o = blockIdx.x * blockDim.x + threadIdx.x;
    double s = 0.0, q = 0.0;
    for (int c = 0; c < CH; ++c) {
        s += psum[(size_t)c * N + o];
        q += psq [(size_t)c * N + o];
    }
    const double m = s / 4096.0;
    meanv[o] = m;
    varv[o]  = q / 4096.0 - m * m;
}

__global__ __launch_bounds__(256) void bn_lif(
    const double* __restrict__ H,
    const double* __restrict__ meanv, const double* __restrict__ varv,
    const float* __restrict__ gamma, const float* __restrict__ beta_bn,
    const float* __restrict__ mem_init,
    const float* __restrict__ lif_beta, const float* __restrict__ thr,
    float* __restrict__ out)
{
    constexpr int T = 64, F = 2048;
    const int gid = blockIdx.x * 256 + threadIdx.x;
    const int o = gid & (F - 1);
    const int b = gid >> 11;

    const double m      = meanv[o];
    const double invstd = 1.0 / sqrt(varv[o] + 1e-5);
    const double sc     = invstd * (double)gamma[o];
    const double sh     = (double)beta_bn[o];
    const double beta_c = fmin(fmax((double)lif_beta[0], 0.0), 1.0);
    const double th     = (double)thr[0];

    double mem = (double)mem_init[gid];
    const double* hp = H   + (size_t)b * T * F + o;
    float*        op = out + (size_t)b * T * F + o;

    for (int t = 0; t < T; ++t) {
        const double h  = hp[(size_t)t * F];
        const double xt = (h - m) * sc + sh;
        const double reset = (mem > th) ? th : 0.0;
        mem = fma(beta_c, mem, xt) - reset;
        op[(size_t)t * F] = (mem > th) ? 1.0f : 0.0f;
    }
}

extern "C" void kernel_launch(void* const* d_in, const int* in_sizes, int n_in,
                              void* d_out, int out_size, void* d_ws, size_t ws_size,
                              hipStream_t stream)
{
    const float* x        = (const float*)d_in[0];
    const float* mem_init = (const float*)d_in[1];
    const float* W        = (const float*)d_in[2];
    const float* b        = (const float*)d_in[3];
    const float* gamma    = (const float*)d_in[4];
    const float* beta_bn  = (const float*)d_in[5];
    const float* lif_beta = (const float*)d_in[6];
    const float* thr      = (const float*)d_in[7];
    float* out = (float*)d_out;

    char* ws = (char*)d_ws;
    double* H     = (double*)ws;                                  // 64 MiB
    double* psum  = (double*)(ws + (size_t)67108864);
    double* psq   = (double*)(ws + (size_t)67108864 + 524288);
    double* meanv = (double*)(ws + (size_t)67108864 + 2 * 524288);
    double* varv  = meanv + 2048;

    // A/B probe: gemm_a result is fully overwritten by gemm_b (authoritative);
    // both dispatches show up separately in rocprof.
    gemm_a     <<<dim3(32, 32), 256, 0, stream>>>(x, W, b, H);
    gemm_b     <<<dim3(32, 16), 256, 0, stream>>>(x, W, b, H);
    bn_partial <<<dim3(8, 32),  256, 0, stream>>>(H, psum, psq);
    bn_finalize<<<8,            256, 0, stream>>>(psum, psq, meanv, varv);
    bn_lif     <<<512,          256, 0, stream>>>(H, meanv, varv, gamma, beta_bn,
                                                  mem_init, lif_beta, thr, out);
}

// Round 6
// 796.874 us; speedup vs baseline: 9.3306x; 9.3306x over previous
//
#include <hip/hip_runtime.h>

// B=64, T=64 -> GEMM M=4096, N=2048, K=2048 ; tdBN ; LIF scan. Full f64
// results (r1/r4: absmax == 0.0). Round 6: same verified r4 structure, but
// LDS holds raw f32 (convert f64 at fragment read). LDS bytes/FLOP halves
// (1.0 -> 0.5) so the 128 B/cy LDS pipe stops co-saturating with the f64
// FMA pipe. Fragments = contiguous 8 f32 -> ds_read_b128 x2 per matrix,
// stride-12-word groups: 16B-aligned, <=2-way banks (free). All LDS reads
// into NAMED scalars (round-5 lesson: casted local arrays -> scratch).

#define KDIM 2048
#define NDIM 2048
#define LROW 192   // 16 groups * 12 words (8 data + 4 pad)

__global__ __launch_bounds__(256, 2) void gemm_f64_v3(
    const float* __restrict__ X,   // (4096, 2048)
    const float* __restrict__ W,   // (2048, 2048)
    const float* __restrict__ bias,
    double* __restrict__ H)        // (4096, 2048)
{
    constexpr int NT = KDIM / 16;
    __shared__ __align__(16) float As[2][16][LROW];
    __shared__ __align__(16) float Bs[2][16][LROW];

    const int tid = threadIdx.x;
    const int tx = tid & 15, ty = tid >> 4;
    const int bm = blockIdx.x * 128, bn = blockIdx.y * 128;

    // staging: thread t owns row (t>>1), k-offset (t&1)*8 (8 floats/matrix)
    const int arow = tid >> 1;
    const int akof = (tid & 1) * 8;
    const float* xa = X + (size_t)(bm + arow) * KDIM + akof;
    const float* wa = W + (size_t)(bn + arow) * KDIM + akof;
    // row r -> group g=r&15 (owner thread), slot h=r>>4 ; word = g*12+h
    const int wslot = (arow & 15) * 12 + (arow >> 4);
    const int abase = ty * 12;   // 8 contiguous f32 (rows ty+16s)
    const int bbase = tx * 12;   // 8 contiguous f32 (cols tx+16s)

    double acc[8][8] = {};

#define STAGE(buf, va0, va1, vb0, vb1) do { \
    As[buf][akof+0][wslot]=va0.x; As[buf][akof+1][wslot]=va0.y; \
    As[buf][akof+2][wslot]=va0.z; As[buf][akof+3][wslot]=va0.w; \
    As[buf][akof+4][wslot]=va1.x; As[buf][akof+5][wslot]=va1.y; \
    As[buf][akof+6][wslot]=va1.z; As[buf][akof+7][wslot]=va1.w; \
    Bs[buf][akof+0][wslot]=vb0.x; Bs[buf][akof+1][wslot]=vb0.y; \
    Bs[buf][akof+2][wslot]=vb0.z; Bs[buf][akof+3][wslot]=vb0.w; \
    Bs[buf][akof+4][wslot]=vb1.x; Bs[buf][akof+5][wslot]=vb1.y; \
    Bs[buf][akof+6][wslot]=vb1.z; Bs[buf][akof+7][wslot]=vb1.w; } while (0)

    {   // prologue: stage k-tile 0
        float4 a0 = *(const float4*)xa;
        float4 a1 = *(const float4*)(xa + 4);
        float4 b0 = *(const float4*)wa;
        float4 b1 = *(const float4*)(wa + 4);
        STAGE(0, a0, a1, b0, b1);
    }
    __syncthreads();

    int cur = 0;
    for (int t = 0; t < NT; ++t) {
        const bool more = (t + 1) < NT;
        float4 pa0, pa1, pb0, pb1;
        if (more) {
            const int k0 = (t + 1) * 16;
            pa0 = *(const float4*)(xa + k0);
            pa1 = *(const float4*)(xa + k0 + 4);
            pb0 = *(const float4*)(wa + k0);
            pb1 = *(const float4*)(wa + k0 + 4);
        }

        #pragma unroll 2
        for (int kk = 0; kk < 16; ++kk) {
            const float4 fa0 = *(const float4*)&As[cur][kk][abase];
            const float4 fa1 = *(const float4*)&As[cur][kk][abase + 4];
            const float4 fb0 = *(const float4*)&Bs[cur][kk][bbase];
            const float4 fb1 = *(const float4*)&Bs[cur][kk][bbase + 4];
            const double a0 = fa0.x, a1 = fa0.y, a2 = fa0.z, a3 = fa0.w;
            const double a4 = fa1.x, a5 = fa1.y, a6 = fa1.z, a7 = fa1.w;
            const double b0 = fb0.x, b1 = fb0.y, b2 = fb0.z, b3 = fb0.w;
            const double b4 = fb1.x, b5 = fb1.y, b6 = fb1.z, b7 = fb1.w;
#define FMAROW(i, ai) \
            acc[i][0]=fma(ai,b0,acc[i][0]); acc[i][1]=fma(ai,b1,acc[i][1]); \
            acc[i][2]=fma(ai,b2,acc[i][2]); acc[i][3]=fma(ai,b3,acc[i][3]); \
            acc[i][4]=fma(ai,b4,acc[i][4]); acc[i][5]=fma(ai,b5,acc[i][5]); \
            acc[i][6]=fma(ai,b6,acc[i][6]); acc[i][7]=fma(ai,b7,acc[i][7]);
            FMAROW(0, a0) FMAROW(1, a1) FMAROW(2, a2) FMAROW(3, a3)
            FMAROW(4, a4) FMAROW(5, a5) FMAROW(6, a6) FMAROW(7, a7)
#undef FMAROW
        }

        if (more) STAGE(cur ^ 1, pa0, pa1, pb0, pb1);
        __syncthreads();
        cur ^= 1;
    }

    // epilogue: rows {bm+ty+16i}, cols {bn+tx+16j}  (identical to r4)
    #pragma unroll
    for (int j = 0; j < 8; ++j) {
        const int col = bn + tx + 16 * j;
        const double bj = (double)bias[col];
        #pragma unroll
        for (int i = 0; i < 8; ++i)
            H[(size_t)(bm + ty + 16 * i) * NDIM + col] = acc[i][j] + bj;
    }
}

// ---------------- epilogue chain (unchanged, verified r1/r4) ----------------
__global__ __launch_bounds__(256) void bn_partial(
    const double* __restrict__ H, double* __restrict__ psum, double* __restrict__ psq)
{
    constexpr int N = 2048, ROWS = 128;
    const int o  = blockIdx.x * 256 + threadIdx.x;
    const int t0 = blockIdx.y * ROWS;
    double s = 0.0, q = 0.0;
    for (int r = 0; r < ROWS; ++r) {
        double h = H[(size_t)(t0 + r) * N + o];
        s += h;
        q = fma(h, h, q);
    }
    psum[(size_t)blockIdx.y * N + o] = s;
    psq [(size_t)blockIdx.y * N + o] = q;
}

__global__ void bn_finalize(const double* __restrict__ psum, const double* __restrict__ psq,
                            double* __restrict__ meanv, double* __restrict__ varv)
{
    constexpr int N = 2048, CH = 32;
    const int o = blockIdx.x * blockDim.x + threadIdx.x;
    double s = 0.0, q = 0.0;
    for (int c = 0; c < CH; ++c) {
        s += psum[(size_t)c * N + o];
        q += psq [(size_t)c * N + o];
    }
    const double m = s / 4096.0;
    meanv[o] = m;
    varv[o]  = q / 4096.0 - m * m;
}

__global__ __launch_bounds__(256) void bn_lif(
    const double* __restrict__ H,
    const double* __restrict__ meanv, const double* __restrict__ varv,
    const float* __restrict__ gamma, const float* __restrict__ beta_bn,
    const float* __restrict__ mem_init,
    const float* __restrict__ lif_beta, const float* __restrict__ thr,
    float* __restrict__ out)
{
    constexpr int T = 64, F = 2048;
    const int gid = blockIdx.x * 256 + threadIdx.x;
    const int o = gid & (F - 1);
    const int b = gid >> 11;

    const double m      = meanv[o];
    const double invstd = 1.0 / sqrt(varv[o] + 1e-5);
    const double sc     = invstd * (double)gamma[o];
    const double sh     = (double)beta_bn[o];
    const double beta_c = fmin(fmax((double)lif_beta[0], 0.0), 1.0);
    const double th     = (double)thr[0];

    double mem = (double)mem_init[gid];
    const double* hp = H   + (size_t)b * T * F + o;
    float*        op = out + (size_t)b * T * F + o;

    for (int t = 0; t < T; ++t) {
        const double h  = hp[(size_t)t * F];
        const double xt = (h - m) * sc + sh;
        const double reset = (mem > th) ? th : 0.0;
        mem = fma(beta_c, mem, xt) - reset;
        op[(size_t)t * F] = (mem > th) ? 1.0f : 0.0f;
    }
}

extern "C" void kernel_launch(void* const* d_in, const int* in_sizes, int n_in,
                              void* d_out, int out_size, void* d_ws, size_t ws_size,
                              hipStream_t stream)
{
    const float* x        = (const float*)d_in[0];
    const float* mem_init = (const float*)d_in[1];
    const float* W        = (const float*)d_in[2];
    const float* b        = (const float*)d_in[3];
    const float* gamma    = (const float*)d_in[4];
    const float* beta_bn  = (const float*)d_in[5];
    const float* lif_beta = (const float*)d_in[6];
    const float* thr      = (const float*)d_in[7];
    float* out = (float*)d_out;

    char* ws = (char*)d_ws;
    double* H     = (double*)ws;                                  // 64 MiB
    double* psum  = (double*)(ws + (size_t)67108864);
    double* psq   = (double*)(ws + (size_t)67108864 + 524288);
    double* meanv = (double*)(ws + (size_t)67108864 + 2 * 524288);
    double* varv  = meanv + 2048;

    gemm_f64_v3<<<dim3(32, 16), 256, 0, stream>>>(x, W, b, H);
    bn_partial <<<dim3(8, 32),  256, 0, stream>>>(H, psum, psq);
    bn_finalize<<<8,            256, 0, stream>>>(psum, psq, meanv, varv);
    bn_lif     <<<512,          256, 0, stream>>>(H, meanv, varv, gamma, beta_bn,
                                                  mem_init, lif_beta, thr, out);
}

// Round 7
// 639.094 us; speedup vs baseline: 11.6341x; 1.2469x over previous
//
#include <hip/hip_runtime.h>

// B=64, T=64 -> GEMM M=4096, N=2048, K=2048 ; tdBN ; LIF scan. Full f64
// results (r1/r4/r6: absmax == 0.0). Round 7: GEMM on v_mfma_f64_16x16x4
// (78.6 TF matrix pipe; VALU path is latency-capped at 789us, r4==r6).
// The f64 MFMA fragment layout is UNVERIFIED on gfx950 (r2/r3 failure), so
// the kernel self-calibrates: one probe MFMA with injective asymmetric
// inputs (A=lane+1, B=(lane+1)^2) is checked against 16 hypotheses
// {A-pack P/Q} x {B-pack P/Q} x {4 D-layouts}; this space also covers
// operand-role swap (== (P,P,transposed D)). The winner selects fragment
// addressing (once, pre-loop) and the epilogue. Probe is exact small-int
// f64 math -> ballot equality is well-defined.

typedef double double4v __attribute__((ext_vector_type(4)));

#define KDIM 2048
#define NDIM 2048
#define LROW 132   // 128 rows + 4 pad (f32 words): 2-way banks max

__global__ __launch_bounds__(256, 2) void gemm_f64_mfma2(
    const float* __restrict__ X,   // (4096, 2048)
    const float* __restrict__ W,   // (2048, 2048)
    const float* __restrict__ bias,
    double* __restrict__ H)        // (4096, 2048)
{
    constexpr int NT = KDIM / 16;
    __shared__ float As[2][16][LROW];
    __shared__ float Bs[2][16][LROW];

    const int tid  = threadIdx.x;
    const int lane = tid & 63;
    const int wid  = tid >> 6;
    const int lf = lane & 15, lq = lane >> 4;
    const int bm = blockIdx.x * 128, bn = blockIdx.y * 128;
    const int wr = wid >> 1, wc = wid & 1;      // wave -> 64x64 quadrant

    // ---------------- layout self-calibration probe ----------------
    double4v pd = (double4v){0.0, 0.0, 0.0, 0.0};
    pd = __builtin_amdgcn_mfma_f64_16x16x4f64(
        (double)(lane + 1), (double)((lane + 1) * (lane + 1)), pd, 0, 0, 0);
    int winner = -1;
    #pragma unroll
    for (int h = 0; h < 16; ++h) {
        const int c1 = h & 1, c2 = (h >> 1) & 1, cd = h >> 2;
        bool ok = true;
        #pragma unroll
        for (int v = 0; v < 4; ++v) {
            const int r16 = (cd == 0) ? 4 * lq + v : (cd == 1) ? lf
                          : (cd == 2) ? lq + 4 * v : lf;
            const int c16 = (cd == 0) ? lf : (cd == 1) ? 4 * lq + v
                          : (cd == 2) ? lf : lq + 4 * v;
            double s = 0.0;
            #pragma unroll
            for (int k = 0; k < 4; ++k) {
                const int i1 = c1 ? (r16 + 16 * k) : (4 * r16 + k);
                const int i2 = c2 ? (c16 + 16 * k) : (4 * c16 + k);
                s += (double)(i1 + 1) * (double)((i2 + 1) * (i2 + 1));
            }
            ok = ok && (pd[v] == s);
        }
        if (__ballot(ok) == ~0ull && winner < 0) winner = h;
    }
    if (winner < 0) winner = 0;   // (all-miss: deterministic fallback)
    const int selA = winner & 1, selB = (winner >> 1) & 1, selD = winner >> 2;

    // fragment addressing per winning packing (computed once)
    const int rlA = selA ? lf : (lane >> 2);
    const int klA = selA ? lq : (lane & 3);
    const int rlB = selB ? lf : (lane >> 2);
    const int klB = selB ? lq : (lane & 3);
    const int baseA = klA * LROW + wr * 64 + rlA;
    const int baseB = klB * LROW + wc * 64 + rlB;

    // ---------------- staging (r6-verified skeleton, f32 LDS) ----------------
    const int arow = tid >> 1;            // 0..127
    const int akof = (tid & 1) * 8;       // 0 or 8
    const float* xa = X + (size_t)(bm + arow) * KDIM + akof;
    const float* wa = W + (size_t)(bn + arow) * KDIM + akof;

#define STAGE(buf, va0, va1, vb0, vb1) do { \
    As[buf][akof+0][arow]=va0.x; As[buf][akof+1][arow]=va0.y; \
    As[buf][akof+2][arow]=va0.z; As[buf][akof+3][arow]=va0.w; \
    As[buf][akof+4][arow]=va1.x; As[buf][akof+5][arow]=va1.y; \
    As[buf][akof+6][arow]=va1.z; As[buf][akof+7][arow]=va1.w; \
    Bs[buf][akof+0][arow]=vb0.x; Bs[buf][akof+1][arow]=vb0.y; \
    Bs[buf][akof+2][arow]=vb0.z; Bs[buf][akof+3][arow]=vb0.w; \
    Bs[buf][akof+4][arow]=vb1.x; Bs[buf][akof+5][arow]=vb1.y; \
    Bs[buf][akof+6][arow]=vb1.z; Bs[buf][akof+7][arow]=vb1.w; } while (0)

    double4v acc[4][4];
    #pragma unroll
    for (int t = 0; t < 4; ++t)
        #pragma unroll
        for (int u = 0; u < 4; ++u)
            acc[t][u] = (double4v){0.0, 0.0, 0.0, 0.0};

    {   // prologue: stage k-tile 0
        float4 a0 = *(const float4*)xa;
        float4 a1 = *(const float4*)(xa + 4);
        float4 b0 = *(const float4*)wa;
        float4 b1 = *(const float4*)(wa + 4);
        STAGE(0, a0, a1, b0, b1);
    }
    __syncthreads();

    int cur = 0;
    for (int t = 0; t < NT; ++t) {
        const bool more = (t + 1) < NT;
        float4 pa0, pa1, pb0, pb1;
        if (more) {
            const int k0 = (t + 1) * 16;
            pa0 = *(const float4*)(xa + k0);
            pa1 = *(const float4*)(xa + k0 + 4);
            pb0 = *(const float4*)(wa + k0);
            pb1 = *(const float4*)(wa + k0 + 4);
        }

        const float* Af = &As[cur][0][0];
        const float* Bf = &Bs[cur][0][0];
        #pragma unroll
        for (int ks = 0; ks < 4; ++ks) {
            const int ko = 4 * ks * LROW;
            const double fa0 = (double)Af[ko + baseA +  0];
            const double fa1 = (double)Af[ko + baseA + 16];
            const double fa2 = (double)Af[ko + baseA + 32];
            const double fa3 = (double)Af[ko + baseA + 48];
            const double fb0 = (double)Bf[ko + baseB +  0];
            const double fb1 = (double)Bf[ko + baseB + 16];
            const double fb2 = (double)Bf[ko + baseB + 32];
            const double fb3 = (double)Bf[ko + baseB + 48];
#define MM(ti, ui, av, bv) \
            acc[ti][ui] = __builtin_amdgcn_mfma_f64_16x16x4f64(av, bv, acc[ti][ui], 0, 0, 0);
            MM(0,0,fa0,fb0) MM(0,1,fa0,fb1) MM(0,2,fa0,fb2) MM(0,3,fa0,fb3)
            MM(1,0,fa1,fb0) MM(1,1,fa1,fb1) MM(1,2,fa1,fb2) MM(1,3,fa1,fb3)
            MM(2,0,fa2,fb0) MM(2,1,fa2,fb1) MM(2,2,fa2,fb2) MM(2,3,fa2,fb3)
            MM(3,0,fa3,fb0) MM(3,1,fa3,fb1) MM(3,2,fa3,fb2) MM(3,3,fa3,fb3)
#undef MM
        }

        if (more) STAGE(cur ^ 1, pa0, pa1, pb0, pb1);
        __syncthreads();
        cur ^= 1;
    }

    // ---------------- epilogue under winning D-layout ----------------
    #pragma unroll
    for (int v = 0; v < 4; ++v) {
        const int r16 = (selD == 0) ? 4 * lq + v : (selD == 1) ? lf
                      : (selD == 2) ? lq + 4 * v : lf;
        const int c16 = (selD == 0) ? lf : (selD == 1) ? 4 * lq + v
                      : (selD == 2) ? lf : lq + 4 * v;
        #pragma unroll
        for (int t = 0; t < 4; ++t) {
            const int row = bm + wr * 64 + 16 * t + r16;
            #pragma unroll
            for (int u = 0; u < 4; ++u) {
                const int col = bn + wc * 64 + 16 * u + c16;
                H[(size_t)row * NDIM + col] = acc[t][u][v] + (double)bias[col];
            }
        }
    }
}

// ---------------- epilogue chain (unchanged, verified r1/r4/r6) ----------------
__global__ __launch_bounds__(256) void bn_partial(
    const double* __restrict__ H, double* __restrict__ psum, double* __restrict__ psq)
{
    constexpr int N = 2048, ROWS = 128;
    const int o  = blockIdx.x * 256 + threadIdx.x;
    const int t0 = blockIdx.y * ROWS;
    double s = 0.0, q = 0.0;
    for (int r = 0; r < ROWS; ++r) {
        double h = H[(size_t)(t0 + r) * N + o];
        s += h;
        q = fma(h, h, q);
    }
    psum[(size_t)blockIdx.y * N + o] = s;
    psq [(size_t)blockIdx.y * N + o] = q;
}

__global__ void bn_finalize(const double* __restrict__ psum, const double* __restrict__ psq,
                            double* __restrict__ meanv, double* __restrict__ varv)
{
    constexpr int N = 2048, CH = 32;
    const int o = blockIdx.x * blockDim.x + threadIdx.x;
    double s = 0.0, q = 0.0;
    for (int c = 0; c < CH; ++c) {
        s += psum[(size_t)c * N + o];
        q += psq [(size_t)c * N + o];
    }
    const double m = s / 4096.0;
    meanv[o] = m;
    varv[o]  = q / 4096.0 - m * m;
}

__global__ __launch_bounds__(256) void bn_lif(
    const double* __restrict__ H,
    const double* __restrict__ meanv, const double* __restrict__ varv,
    const float* __restrict__ gamma, const float* __restrict__ beta_bn,
    const float* __restrict__ mem_init,
    const float* __restrict__ lif_beta, const float* __restrict__ thr,
    float* __restrict__ out)
{
    constexpr int T = 64, F = 2048;
    const int gid = blockIdx.x * 256 + threadIdx.x;
    const int o = gid & (F - 1);
    const int b = gid >> 11;

    const double m      = meanv[o];
    const double invstd = 1.0 / sqrt(varv[o] + 1e-5);
    const double sc     = invstd * (double)gamma[o];
    const double sh     = (double)beta_bn[o];
    const double beta_c = fmin(fmax((double)lif_beta[0], 0.0), 1.0);
    const double th     = (double)thr[0];

    double mem = (double)mem_init[gid];
    const double* hp = H   + (size_t)b * T * F + o;
    float*        op = out + (size_t)b * T * F + o;

    for (int t = 0; t < T; ++t) {
        const double h  = hp[(size_t)t * F];
        const double xt = (h - m) * sc + sh;
        const double reset = (mem > th) ? th : 0.0;
        mem = fma(beta_c, mem, xt) - reset;
        op[(size_t)t * F] = (mem > th) ? 1.0f : 0.0f;
    }
}

extern "C" void kernel_launch(void* const* d_in, const int* in_sizes, int n_in,
                              void* d_out, int out_size, void* d_ws, size_t ws_size,
                              hipStream_t stream)
{
    const float* x        = (const float*)d_in[0];
    const float* mem_init = (const float*)d_in[1];
    const float* W        = (const float*)d_in[2];
    const float* b        = (const float*)d_in[3];
    const float* gamma    = (const float*)d_in[4];
    const float* beta_bn  = (const float*)d_in[5];
    const float* lif_beta = (const float*)d_in[6];
    const float* thr      = (const float*)d_in[7];
    float* out = (float*)d_out;

    char* ws = (char*)d_ws;
    double* H     = (double*)ws;                                  // 64 MiB
    double* psum  = (double*)(ws + (size_t)67108864);
    double* psq   = (double*)(ws + (size_t)67108864 + 524288);
    double* meanv = (double*)(ws + (size_t)67108864 + 2 * 524288);
    double* varv  = meanv + 2048;

    gemm_f64_mfma2<<<dim3(32, 16), 256, 0, stream>>>(x, W, b, H);
    bn_partial    <<<dim3(8, 32),  256, 0, stream>>>(H, psum, psq);
    bn_finalize   <<<8,            256, 0, stream>>>(psum, psq, meanv, varv);
    bn_lif        <<<512,          256, 0, stream>>>(H, meanv, varv, gamma, beta_bn,
                                                     mem_init, lif_beta, thr, out);
}

// Round 8
// 637.244 us; speedup vs baseline: 11.6679x; 1.0029x over previous
//
#include <hip/hip_runtime.h>

// B=64, T=64 -> GEMM M=4096, N=2048, K=2048 ; tdBN ; LIF scan. Full f64
// results (r1/r4/r6/r7: absmax == 0.0). Round 8: r7's self-calibrating
// v_mfma_f64_16x16x4 GEMM (578us, MfmaUtil 81%) with the LDS issue-path
// slimmed:
//  - permuted row layout pos=(r6&15)*4+(r6>>4): each lane's 4 fragment
//    values (t=0..3 row-tiles at fixed k) are contiguous -> ds_read_b128
//    (was 4x scalar b32, 4-way conflicted)
//  - BK 16->32: half the barriers (64 iters), LDS exactly 64 KB static
// Runtime layout calibration (16 hypotheses) retained verbatim from r7 —
// fragment addressing is generic in the calibrated (rl, kl).

typedef double double4v __attribute__((ext_vector_type(4)));

#define KDIM 2048
#define NDIM 2048
#define BKt  32
#define LROW 128

__global__ __launch_bounds__(256, 2) void gemm_f64_mfma3(
    const float* __restrict__ X,   // (4096, 2048)
    const float* __restrict__ W,   // (2048, 2048)
    const float* __restrict__ bias,
    double* __restrict__ H)        // (4096, 2048)
{
    constexpr int NT = KDIM / BKt;           // 64
    __shared__ float As[2][BKt][LROW];       // 32 KB
    __shared__ float Bs[2][BKt][LROW];       // 32 KB

    const int tid  = threadIdx.x;
    const int lane = tid & 63;
    const int wid  = tid >> 6;
    const int lf = lane & 15, lq = lane >> 4;
    const int bm = blockIdx.x * 128, bn = blockIdx.y * 128;
    const int wr = wid >> 1, wc = wid & 1;      // wave -> 64x64 quadrant

    // ---------------- layout self-calibration probe (r7-verified) ----------------
    double4v pd = (double4v){0.0, 0.0, 0.0, 0.0};
    pd = __builtin_amdgcn_mfma_f64_16x16x4f64(
        (double)(lane + 1), (double)((lane + 1) * (lane + 1)), pd, 0, 0, 0);
    int winner = -1;
    #pragma unroll
    for (int h = 0; h < 16; ++h) {
        const int c1 = h & 1, c2 = (h >> 1) & 1, cd = h >> 2;
        bool ok = true;
        #pragma unroll
        for (int v = 0; v < 4; ++v) {
            const int r16 = (cd == 0) ? 4 * lq + v : (cd == 1) ? lf
                          : (cd == 2) ? lq + 4 * v : lf;
            const int c16 = (cd == 0) ? lf : (cd == 1) ? 4 * lq + v
                          : (cd == 2) ? lf : lq + 4 * v;
            double s = 0.0;
            #pragma unroll
            for (int k = 0; k < 4; ++k) {
                const int i1 = c1 ? (r16 + 16 * k) : (4 * r16 + k);
                const int i2 = c2 ? (c16 + 16 * k) : (4 * c16 + k);
                s += (double)(i1 + 1) * (double)((i2 + 1) * (i2 + 1));
            }
            ok = ok && (pd[v] == s);
        }
        if (__ballot(ok) == ~0ull && winner < 0) winner = h;
    }
    if (winner < 0) winner = 0;
    const int selA = winner & 1, selB = (winner >> 1) & 1, selD = winner >> 2;

    const int rlA = selA ? lf : (lane >> 2);
    const int klA = selA ? lq : (lane & 3);
    const int rlB = selB ? lf : (lane >> 2);
    const int klB = selB ? lq : (lane & 3);
    // permuted layout: lane's 4 t-values contiguous at rl*4 (within quadrant)
    const int baseA = klA * LROW + wr * 64 + rlA * 4;
    const int baseB = klB * LROW + wc * 64 + rlB * 4;

    // ---------------- staging ----------------
    const int arow = tid >> 1;            // 0..127
    const int kofs = (tid & 1) * 16;      // 0 or 16
    const float* xa = X + (size_t)(bm + arow) * KDIM + kofs;
    const float* wa = W + (size_t)(bn + arow) * KDIM + kofs;
    const int r6  = arow & 63;
    const int pos = (arow >> 6) * 64 + (r6 & 15) * 4 + (r6 >> 4);

#define STAGE(buf, A0, A1, A2, A3, B0, B1, B2, B3) do { \
    As[buf][kofs+ 0][pos]=A0.x; As[buf][kofs+ 1][pos]=A0.y; \
    As[buf][kofs+ 2][pos]=A0.z; As[buf][kofs+ 3][pos]=A0.w; \
    As[buf][kofs+ 4][pos]=A1.x; As[buf][kofs+ 5][pos]=A1.y; \
    As[buf][kofs+ 6][pos]=A1.z; As[buf][kofs+ 7][pos]=A1.w; \
    As[buf][kofs+ 8][pos]=A2.x; As[buf][kofs+ 9][pos]=A2.y; \
    As[buf][kofs+10][pos]=A2.z; As[buf][kofs+11][pos]=A2.w; \
    As[buf][kofs+12][pos]=A3.x; As[buf][kofs+13][pos]=A3.y; \
    As[buf][kofs+14][pos]=A3.z; As[buf][kofs+15][pos]=A3.w; \
    Bs[buf][kofs+ 0][pos]=B0.x; Bs[buf][kofs+ 1][pos]=B0.y; \
    Bs[buf][kofs+ 2][pos]=B0.z; Bs[buf][kofs+ 3][pos]=B0.w; \
    Bs[buf][kofs+ 4][pos]=B1.x; Bs[buf][kofs+ 5][pos]=B1.y; \
    Bs[buf][kofs+ 6][pos]=B1.z; Bs[buf][kofs+ 7][pos]=B1.w; \
    Bs[buf][kofs+ 8][pos]=B2.x; Bs[buf][kofs+ 9][pos]=B2.y; \
    Bs[buf][kofs+10][pos]=B2.z; Bs[buf][kofs+11][pos]=B2.w; \
    Bs[buf][kofs+12][pos]=B3.x; Bs[buf][kofs+13][pos]=B3.y; \
    Bs[buf][kofs+14][pos]=B3.z; Bs[buf][kofs+15][pos]=B3.w; } while (0)

    double4v acc[4][4];
    #pragma unroll
    for (int t = 0; t < 4; ++t)
        #pragma unroll
        for (int u = 0; u < 4; ++u)
            acc[t][u] = (double4v){0.0, 0.0, 0.0, 0.0};

    {   // prologue: stage k-tile 0
        float4 a0 = *(const float4*)(xa);
        float4 a1 = *(const float4*)(xa + 4);
        float4 a2 = *(const float4*)(xa + 8);
        float4 a3 = *(const float4*)(xa + 12);
        float4 b0 = *(const float4*)(wa);
        float4 b1 = *(const float4*)(wa + 4);
        float4 b2 = *(const float4*)(wa + 8);
        float4 b3 = *(const float4*)(wa + 12);
        STAGE(0, a0, a1, a2, a3, b0, b1, b2, b3);
    }
    __syncthreads();

    int cur = 0;
    for (int t = 0; t < NT; ++t) {
        const bool more = (t + 1) < NT;
        float4 pa0, pa1, pa2, pa3, pb0, pb1, pb2, pb3;
        if (more) {
            const int k0 = (t + 1) * BKt;
            pa0 = *(const float4*)(xa + k0);
            pa1 = *(const float4*)(xa + k0 + 4);
            pa2 = *(const float4*)(xa + k0 + 8);
            pa3 = *(const float4*)(xa + k0 + 12);
            pb0 = *(const float4*)(wa + k0);
            pb1 = *(const float4*)(wa + k0 + 4);
            pb2 = *(const float4*)(wa + k0 + 8);
            pb3 = *(const float4*)(wa + k0 + 12);
        }

        const float* Af = &As[cur][0][0];
        const float* Bf = &Bs[cur][0][0];
        #pragma unroll
        for (int ks = 0; ks < 8; ++ks) {
            const float4 fa = *(const float4*)&Af[4 * ks * LROW + baseA];
            const float4 fb = *(const float4*)&Bf[4 * ks * LROW + baseB];
            const double fa0 = fa.x, fa1 = fa.y, fa2 = fa.z, fa3 = fa.w;
            const double fb0 = fb.x, fb1 = fb.y, fb2 = fb.z, fb3 = fb.w;
#define MM(ti, ui, av, bv) \
            acc[ti][ui] = __builtin_amdgcn_mfma_f64_16x16x4f64(av, bv, acc[ti][ui], 0, 0, 0);
            MM(0,0,fa0,fb0) MM(0,1,fa0,fb1) MM(0,2,fa0,fb2) MM(0,3,fa0,fb3)
            MM(1,0,fa1,fb0) MM(1,1,fa1,fb1) MM(1,2,fa1,fb2) MM(1,3,fa1,fb3)
            MM(2,0,fa2,fb0) MM(2,1,fa2,fb1) MM(2,2,fa2,fb2) MM(2,3,fa2,fb3)
            MM(3,0,fa3,fb0) MM(3,1,fa3,fb1) MM(3,2,fa3,fb2) MM(3,3,fa3,fb3)
#undef MM
        }

        if (more) STAGE(cur ^ 1, pa0, pa1, pa2, pa3, pb0, pb1, pb2, pb3);
        __syncthreads();
        cur ^= 1;
    }

    // ---------------- epilogue under winning D-layout (r7-verified) ----------------
    #pragma unroll
    for (int v = 0; v < 4; ++v) {
        const int r16 = (selD == 0) ? 4 * lq + v : (selD == 1) ? lf
                      : (selD == 2) ? lq + 4 * v : lf;
        const int c16 = (selD == 0) ? lf : (selD == 1) ? 4 * lq + v
                      : (selD == 2) ? lf : lq + 4 * v;
        #pragma unroll
        for (int t = 0; t < 4; ++t) {
            const int row = bm + wr * 64 + 16 * t + r16;
            #pragma unroll
            for (int u = 0; u < 4; ++u) {
                const int col = bn + wc * 64 + 16 * u + c16;
                H[(size_t)row * NDIM + col] = acc[t][u][v] + (double)bias[col];
            }
        }
    }
}

// ---------------- epilogue chain (unchanged, verified r1/r4/r6/r7) ----------------
__global__ __launch_bounds__(256) void bn_partial(
    const double* __restrict__ H, double* __restrict__ psum, double* __restrict__ psq)
{
    constexpr int N = 2048, ROWS = 128;
    const int o  = blockIdx.x * 256 + threadIdx.x;
    const int t0 = blockIdx.y * ROWS;
    double s = 0.0, q = 0.0;
    for (int r = 0; r < ROWS; ++r) {
        double h = H[(size_t)(t0 + r) * N + o];
        s += h;
        q = fma(h, h, q);
    }
    psum[(size_t)blockIdx.y * N + o] = s;
    psq [(size_t)blockIdx.y * N + o] = q;
}

__global__ void bn_finalize(const double* __restrict__ psum, const double* __restrict__ psq,
                            double* __restrict__ meanv, double* __restrict__ varv)
{
    constexpr int N = 2048, CH = 32;
    const int o = blockIdx.x * blockDim.x + threadIdx.x;
    double s = 0.0, q = 0.0;
    for (int c = 0; c < CH; ++c) {
        s += psum[(size_t)c * N + o];
        q += psq [(size_t)c * N + o];
    }
    const double m = s / 4096.0;
    meanv[o] = m;
    varv[o]  = q / 4096.0 - m * m;
}

__global__ __launch_bounds__(256) void bn_lif(
    const double* __restrict__ H,
    const double* __restrict__ meanv, const double* __restrict__ varv,
    const float* __restrict__ gamma, const float* __restrict__ beta_bn,
    const float* __restrict__ mem_init,
    const float* __restrict__ lif_beta, const float* __restrict__ thr,
    float* __restrict__ out)
{
    constexpr int T = 64, F = 2048;
    const int gid = blockIdx.x * 256 + threadIdx.x;
    const int o = gid & (F - 1);
    const int b = gid >> 11;

    const double m      = meanv[o];
    const double invstd = 1.0 / sqrt(varv[o] + 1e-5);
    const double sc     = invstd * (double)gamma[o];
    const double sh     = (double)beta_bn[o];
    const double beta_c = fmin(fmax((double)lif_beta[0], 0.0), 1.0);
    const double th     = (double)thr[0];

    double mem = (double)mem_init[gid];
    const double* hp = H   + (size_t)b * T * F + o;
    float*        op = out + (size_t)b * T * F + o;

    for (int t = 0; t < T; ++t) {
        const double h  = hp[(size_t)t * F];
        const double xt = (h - m) * sc + sh;
        const double reset = (mem > th) ? th : 0.0;
        mem = fma(beta_c, mem, xt) - reset;
        op[(size_t)t * F] = (mem > th) ? 1.0f : 0.0f;
    }
}

extern "C" void kernel_launch(void* const* d_in, const int* in_sizes, int n_in,
                              void* d_out, int out_size, void* d_ws, size_t ws_size,
                              hipStream_t stream)
{
    const float* x        = (const float*)d_in[0];
    const float* mem_init = (const float*)d_in[1];
    const float* W        = (const float*)d_in[2];
    const float* b        = (const float*)d_in[3];
    const float* gamma    = (const float*)d_in[4];
    const float* beta_bn  = (const float*)d_in[5];
    const float* lif_beta = (const float*)d_in[6];
    const float* thr      = (const float*)d_in[7];
    float* out = (float*)d_out;

    char* ws = (char*)d_ws;
    double* H     = (double*)ws;                                  // 64 MiB
    double* psum  = (double*)(ws + (size_t)67108864);
    double* psq   = (double*)(ws + (size_t)67108864 + 524288);
    double* meanv = (double*)(ws + (size_t)67108864 + 2 * 524288);
    double* varv  = meanv + 2048;

    gemm_f64_mfma3<<<dim3(32, 16), 256, 0, stream>>>(x, W, b, H);
    bn_partial    <<<dim3(8, 32),  256, 0, stream>>>(H, psum, psq);
    bn_finalize   <<<8,            256, 0, stream>>>(psum, psq, meanv, varv);
    bn_lif        <<<512,          256, 0, stream>>>(H, meanv, varv, gamma, beta_bn,
                                                     mem_init, lif_beta, thr, out);
}